// Round 1
// baseline (7701.032 us; speedup 1.0000x reference)
//
#include <hip/hip_runtime.h>
#include <hip/hip_fp16.h>

// Problem constants
#define BATCH 64
#define NTOK 785          // 1 + 28*28
#define CDIM 768
#define NHEAD 12
#define HDIM 64
#define ANUM 49
#define WIN 28
#define MROWS (BATCH * NTOK)   // 50240

// ---------------- workspace layout (bytes) ----------------
// q16/k16/v16: (B, H, N, 64) halves, y16: (B, N, C) halves
#define SZ_Q ((size_t)BATCH * NHEAD * NTOK * HDIM * 2)   // 77,168,640
#define OFF_Q  ((size_t)0)
#define OFF_K  (OFF_Q + SZ_Q)
#define OFF_V  (OFF_K + SZ_Q)
#define OFF_Y  (OFF_V + SZ_Q)
#define SZ_AG  ((size_t)BATCH * NHEAD * ANUM * HDIM * 4) // 9,633,792
#define OFF_AG (OFF_Y + SZ_Q)
#define OFF_AV (OFF_AG + SZ_AG)
#define SZ_B   ((size_t)NHEAD * ANUM * NTOK * 4)         // 1,846,320
#define OFF_B1 (OFF_AV + SZ_AG)
#define OFF_B2 (OFF_B1 + SZ_B)

// ---------------- bilinear (jax.image.resize, half-pixel centers, 7->28) ----
__device__ __forceinline__ float bilin7(const float* __restrict__ t, int y, int x) {
    float fy = 0.25f * (float)y - 0.375f;
    float fx = 0.25f * (float)x - 0.375f;
    int y0 = (int)floorf(fy);
    int x0 = (int)floorf(fx);
    float wy = fy - (float)y0, wx = fx - (float)x0;
    int y0c = max(0, min(6, y0)),     y1c = max(0, min(6, y0 + 1));
    int x0c = max(0, min(6, x0)),     x1c = max(0, min(6, x0 + 1));
    float v00 = t[y0c * 7 + x0c], v01 = t[y0c * 7 + x1c];
    float v10 = t[y1c * 7 + x0c], v11 = t[y1c * 7 + x1c];
    return (1.f - wy) * ((1.f - wx) * v00 + wx * v01) +
           wy        * ((1.f - wx) * v10 + wx * v11);
}

// ---------------- bias kernel: builds bias1[h][a][n] and bias2[h][n][a] -----
__global__ void bias_kernel(const float* __restrict__ an, const float* __restrict__ ah,
                            const float* __restrict__ aw, const float* __restrict__ ac,
                            const float* __restrict__ na, const float* __restrict__ ha,
                            const float* __restrict__ wa, const float* __restrict__ ca,
                            float* __restrict__ bias1, float* __restrict__ bias2) {
    int idx = blockIdx.x * 256 + threadIdx.x;
    const int total = NHEAD * ANUM * NTOK;
    if (idx >= total) return;
    int h = idx / (ANUM * NTOK);
    int r = idx % (ANUM * NTOK);
    int a = r / NTOK;
    int n = r % NTOK;
    float v1, v2;
    if (n == 0) {
        v1 = ac[h * ANUM + a];
        v2 = ca[h * ANUM + a];
    } else {
        int p = n - 1, y = p / WIN, x = p % WIN;
        int haidx = h * ANUM + a;
        v1 = bilin7(an + haidx * 49, y, x) + ah[haidx * WIN + y] + aw[haidx * WIN + x];
        v2 = bilin7(na + haidx * 49, y, x) + ha[(h * WIN + y) * ANUM + a] + wa[(h * WIN + x) * ANUM + a];
    }
    bias1[(h * ANUM + a) * NTOK + n] = v1;
    bias2[((size_t)h * NTOK + n) * ANUM + a] = v2;
}

// ---------------- qkv GEMM: out = x @ w_qkv^T, scattered fp16 store ---------
// A: (50240, 768) f32, W: (2304, 768) f32. 128x128 tile, BK=16, 8x8/thread.
__global__ __launch_bounds__(256) void gemm_qkv(const float* __restrict__ A,
                                                const float* __restrict__ W,
                                                __half* __restrict__ qo,
                                                __half* __restrict__ ko,
                                                __half* __restrict__ vo) {
    __shared__ float As[16][132];
    __shared__ float Bs[16][132];
    const int K = CDIM;
    int tid = threadIdx.x;
    int m0 = blockIdx.x * 128;
    int n0 = blockIdx.y * 128;
    int tm = tid >> 4, tn = tid & 15;
    int lrow = tid >> 2;
    int lcol = (tid & 3) << 2;

    float acc[8][8];
#pragma unroll
    for (int i = 0; i < 8; ++i)
#pragma unroll
        for (int j = 0; j < 8; ++j) acc[i][j] = 0.f;

    int rowA2 = min(m0 + lrow + 64, MROWS - 1);
    const float* Ap  = A + (size_t)(m0 + lrow) * K + lcol;
    const float* Ap2 = A + (size_t)rowA2 * K + lcol;
    const float* Bp  = W + (size_t)(n0 + lrow) * K + lcol;
    const float* Bp2 = W + (size_t)(n0 + lrow + 64) * K + lcol;

    for (int k0 = 0; k0 < K; k0 += 16) {
        float4 a0 = *(const float4*)(Ap + k0);
        float4 a1 = *(const float4*)(Ap2 + k0);
        float4 b0 = *(const float4*)(Bp + k0);
        float4 b1 = *(const float4*)(Bp2 + k0);
        __syncthreads();
        As[lcol + 0][lrow] = a0.x; As[lcol + 1][lrow] = a0.y;
        As[lcol + 2][lrow] = a0.z; As[lcol + 3][lrow] = a0.w;
        As[lcol + 0][lrow + 64] = a1.x; As[lcol + 1][lrow + 64] = a1.y;
        As[lcol + 2][lrow + 64] = a1.z; As[lcol + 3][lrow + 64] = a1.w;
        Bs[lcol + 0][lrow] = b0.x; Bs[lcol + 1][lrow] = b0.y;
        Bs[lcol + 2][lrow] = b0.z; Bs[lcol + 3][lrow] = b0.w;
        Bs[lcol + 0][lrow + 64] = b1.x; Bs[lcol + 1][lrow + 64] = b1.y;
        Bs[lcol + 2][lrow + 64] = b1.z; Bs[lcol + 3][lrow + 64] = b1.w;
        __syncthreads();
#pragma unroll
        for (int kk = 0; kk < 16; ++kk) {
            float av[8], bv[8];
            *(float4*)&av[0] = *(const float4*)&As[kk][tm * 4];
            *(float4*)&av[4] = *(const float4*)&As[kk][64 + tm * 4];
            *(float4*)&bv[0] = *(const float4*)&Bs[kk][tn * 4];
            *(float4*)&bv[4] = *(const float4*)&Bs[kk][64 + tn * 4];
#pragma unroll
            for (int i = 0; i < 8; ++i)
#pragma unroll
                for (int j = 0; j < 8; ++j)
                    acc[i][j] = fmaf(av[i], bv[j], acc[i][j]);
        }
    }

    // scatter store: col j -> tensor t=j/768, h=(j%768)/64, d=j%64
    int t = n0 / CDIM;
    __half* Ob = (t == 0) ? qo : (t == 1) ? ko : vo;
    int h0 = (n0 % CDIM) >> 6;    // cols tn*4..+3 in h0; cols 64+tn*4 in h0+1
#pragma unroll
    for (int rh = 0; rh < 2; ++rh) {
#pragma unroll
        for (int i = 0; i < 4; ++i) {
            int row = m0 + rh * 64 + tm * 4 + i;
            if (row < MROWS) {
                int bb = row / NTOK;
                int nn = row - bb * NTOK;
                size_t base = (((size_t)bb * NHEAD + h0) * NTOK + nn) * HDIM + tn * 4;
                __half* p0 = Ob + base;
                __half* p1 = Ob + base + (size_t)NTOK * HDIM;  // h0+1
#pragma unroll
                for (int j = 0; j < 4; ++j) {
                    p0[j] = __float2half(acc[rh * 4 + i][j]);
                    p1[j] = __float2half(acc[rh * 4 + i][4 + j]);
                }
            }
        }
    }
}

// ---------------- proj GEMM: d_out = y @ w_proj^T + b ----------------------
__global__ __launch_bounds__(256) void gemm_proj(const __half* __restrict__ Y,
                                                 const float* __restrict__ W,
                                                 const float* __restrict__ bias,
                                                 float* __restrict__ D) {
    __shared__ float As[16][132];
    __shared__ float Bs[16][132];
    const int K = CDIM;
    int tid = threadIdx.x;
    int m0 = blockIdx.x * 128;
    int n0 = blockIdx.y * 128;
    int tm = tid >> 4, tn = tid & 15;
    int lrow = tid >> 2;
    int lcol = (tid & 3) << 2;

    float acc[8][8];
#pragma unroll
    for (int i = 0; i < 8; ++i)
#pragma unroll
        for (int j = 0; j < 8; ++j) acc[i][j] = 0.f;

    int rowA2 = min(m0 + lrow + 64, MROWS - 1);
    const __half* Ap  = Y + (size_t)(m0 + lrow) * K + lcol;
    const __half* Ap2 = Y + (size_t)rowA2 * K + lcol;
    const float* Bp  = W + (size_t)(n0 + lrow) * K + lcol;
    const float* Bp2 = W + (size_t)(n0 + lrow + 64) * K + lcol;

    for (int k0 = 0; k0 < K; k0 += 16) {
        float2 ra0 = *(const float2*)(Ap + k0);
        float2 ra1 = *(const float2*)(Ap2 + k0);
        float4 b0 = *(const float4*)(Bp + k0);
        float4 b1 = *(const float4*)(Bp2 + k0);
        __half2 h00 = *(__half2*)&ra0.x, h01 = *(__half2*)&ra0.y;
        __half2 h10 = *(__half2*)&ra1.x, h11 = *(__half2*)&ra1.y;
        float2 f00 = __half22float2(h00), f01 = __half22float2(h01);
        float2 f10 = __half22float2(h10), f11 = __half22float2(h11);
        __syncthreads();
        As[lcol + 0][lrow] = f00.x; As[lcol + 1][lrow] = f00.y;
        As[lcol + 2][lrow] = f01.x; As[lcol + 3][lrow] = f01.y;
        As[lcol + 0][lrow + 64] = f10.x; As[lcol + 1][lrow + 64] = f10.y;
        As[lcol + 2][lrow + 64] = f11.x; As[lcol + 3][lrow + 64] = f11.y;
        Bs[lcol + 0][lrow] = b0.x; Bs[lcol + 1][lrow] = b0.y;
        Bs[lcol + 2][lrow] = b0.z; Bs[lcol + 3][lrow] = b0.w;
        Bs[lcol + 0][lrow + 64] = b1.x; Bs[lcol + 1][lrow + 64] = b1.y;
        Bs[lcol + 2][lrow + 64] = b1.z; Bs[lcol + 3][lrow + 64] = b1.w;
        __syncthreads();
#pragma unroll
        for (int kk = 0; kk < 16; ++kk) {
            float av[8], bv[8];
            *(float4*)&av[0] = *(const float4*)&As[kk][tm * 4];
            *(float4*)&av[4] = *(const float4*)&As[kk][64 + tm * 4];
            *(float4*)&bv[0] = *(const float4*)&Bs[kk][tn * 4];
            *(float4*)&bv[4] = *(const float4*)&Bs[kk][64 + tn * 4];
#pragma unroll
            for (int i = 0; i < 8; ++i)
#pragma unroll
                for (int j = 0; j < 8; ++j)
                    acc[i][j] = fmaf(av[i], bv[j], acc[i][j]);
        }
    }

    float bs0[4], bs1[4];
#pragma unroll
    for (int j = 0; j < 4; ++j) {
        bs0[j] = bias[n0 + tn * 4 + j];
        bs1[j] = bias[n0 + 64 + tn * 4 + j];
    }
#pragma unroll
    for (int rh = 0; rh < 2; ++rh) {
#pragma unroll
        for (int i = 0; i < 4; ++i) {
            int row = m0 + rh * 64 + tm * 4 + i;
            if (row < MROWS) {
                float* dp = D + (size_t)row * CDIM + n0 + tn * 4;
                float4 o0, o1;
                o0.x = acc[rh * 4 + i][0] + bs0[0]; o0.y = acc[rh * 4 + i][1] + bs0[1];
                o0.z = acc[rh * 4 + i][2] + bs0[2]; o0.w = acc[rh * 4 + i][3] + bs0[3];
                o1.x = acc[rh * 4 + i][4] + bs1[0]; o1.y = acc[rh * 4 + i][5] + bs1[1];
                o1.z = acc[rh * 4 + i][6] + bs1[2]; o1.w = acc[rh * 4 + i][7] + bs1[3];
                *(float4*)dp = o0;
                *(float4*)(dp + 64) = o1;
            }
        }
    }
}

// ---------------- agent pooling: 4x4 mean of q image tokens ----------------
__global__ void pool_kernel(const __half* __restrict__ q16, float* __restrict__ agent) {
    int bidx = blockIdx.x;           // (b, h, a)
    int d = threadIdx.x;             // 64 threads
    int b = bidx / (NHEAD * ANUM);
    int r = bidx % (NHEAD * ANUM);
    int h = r / ANUM;
    int a = r % ANUM;
    int py = a / 7, px = a % 7;
    const __half* base = q16 + ((size_t)(b * NHEAD + h) * NTOK) * HDIM;
    float s = 0.f;
#pragma unroll
    for (int dy = 0; dy < 4; ++dy)
#pragma unroll
        for (int dx = 0; dx < 4; ++dx) {
            int n = 1 + (py * 4 + dy) * WIN + (px * 4 + dx);
            s += __half2float(base[(size_t)n * HDIM + d]);
        }
    agent[((size_t)(b * NHEAD + h) * ANUM + a) * HDIM + d] = s * (1.0f / 16.0f);
}

// ---------------- stage 1: agents attend to K/V ----------------------------
__global__ __launch_bounds__(256) void stage1_kernel(const __half* __restrict__ k16,
                                                     const __half* __restrict__ v16,
                                                     const float* __restrict__ agent,
                                                     const float* __restrict__ bias1,
                                                     float* __restrict__ agentv) {
    __shared__ float sA[64];
    __shared__ float sS[NTOK];
    __shared__ float sred[8];
    __shared__ float spv[256];
    int bidx = blockIdx.x;
    int b = bidx / (NHEAD * ANUM);
    int r = bidx % (NHEAD * ANUM);
    int h = r / ANUM;
    int a = r % ANUM;
    int tid = threadIdx.x;
    int lane = tid & 63, wid = tid >> 6;
    size_t bh = (size_t)(b * NHEAD + h);

    if (tid < 64) sA[tid] = agent[(bh * ANUM + a) * HDIM + tid] * 0.125f;
    __syncthreads();

    const __half* kbase = k16 + bh * NTOK * HDIM;
    const float* b1 = bias1 + (h * ANUM + a) * NTOK;
    for (int n = tid; n < NTOK; n += 256) {
        const __half2* kp = (const __half2*)(kbase + (size_t)n * HDIM);
        float dot = 0.f;
#pragma unroll
        for (int i = 0; i < 32; ++i) {
            float2 f = __half22float2(kp[i]);
            dot += sA[2 * i] * f.x + sA[2 * i + 1] * f.y;
        }
        sS[n] = dot + b1[n];
    }
    __syncthreads();

    float m = -1e30f;
    for (int n = tid; n < NTOK; n += 256) m = fmaxf(m, sS[n]);
#pragma unroll
    for (int off = 32; off > 0; off >>= 1) m = fmaxf(m, __shfl_xor(m, off));
    if (lane == 0) sred[wid] = m;
    __syncthreads();
    m = fmaxf(fmaxf(sred[0], sred[1]), fmaxf(sred[2], sred[3]));

    float ps = 0.f;
    for (int n = tid; n < NTOK; n += 256) {
        float e = __expf(sS[n] - m);
        sS[n] = e;
        ps += e;
    }
#pragma unroll
    for (int off = 32; off > 0; off >>= 1) ps += __shfl_xor(ps, off);
    if (lane == 0) sred[4 + wid] = ps;
    __syncthreads();
    float inv = 1.0f / (sred[4] + sred[5] + sred[6] + sred[7]);

    const __half* vbase = v16 + bh * NTOK * HDIM;
    float accv = 0.f;
    for (int n = wid; n < NTOK; n += 4)
        accv += sS[n] * __half2float(vbase[(size_t)n * HDIM + lane]);
    spv[tid] = accv;
    __syncthreads();
    if (tid < 64) {
        float tot = spv[tid] + spv[tid + 64] + spv[tid + 128] + spv[tid + 192];
        agentv[(bh * ANUM + a) * HDIM + tid] = tot * inv;
    }
}

// ---------------- stage 2: queries attend to agents ------------------------
__global__ __launch_bounds__(256) void stage2_kernel(const __half* __restrict__ q16,
                                                     const float* __restrict__ agent,
                                                     const float* __restrict__ agentv,
                                                     const float* __restrict__ bias2,
                                                     __half* __restrict__ y16) {
    int wid = threadIdx.x >> 6, lane = threadIdx.x & 63;
    int r = blockIdx.x * 4 + wid;          // < 602880
    int b = r / (NHEAD * NTOK);
    int rr = r % (NHEAD * NTOK);
    int h = rr / NTOK;
    int n = rr % NTOK;
    size_t bh = (size_t)(b * NHEAD + h);

    float ql = __half2float(q16[(bh * NTOK + n) * HDIM + lane]) * 0.125f;
    const float* ag = agent + bh * ANUM * HDIM;
    const float* av = agentv + bh * ANUM * HDIM;
    float sbias = (lane < ANUM) ? bias2[((size_t)h * NTOK + n) * ANUM + lane] : 0.f;

    float myscore = -1e30f;
    for (int a = 0; a < ANUM; ++a) {
        float t = ql * ag[a * HDIM + lane];
#pragma unroll
        for (int off = 32; off > 0; off >>= 1) t += __shfl_xor(t, off);
        if (lane == a) myscore = t + sbias;
    }
    float m = myscore;
#pragma unroll
    for (int off = 32; off > 0; off >>= 1) m = fmaxf(m, __shfl_xor(m, off));
    float p = (lane < ANUM) ? __expf(myscore - m) : 0.f;
    float s = p;
#pragma unroll
    for (int off = 32; off > 0; off >>= 1) s += __shfl_xor(s, off);
    p /= s;

    float acc = 0.f;
    for (int a = 0; a < ANUM; ++a) {
        float pa = __shfl(p, a);
        acc += pa * av[a * HDIM + lane];
    }
    y16[((size_t)b * NTOK + n) * CDIM + h * HDIM + lane] = __float2half(acc);
}

// ---------------- depthwise 3x3 conv on V image tokens, add into y ---------
__global__ void dwc_kernel(const __half* __restrict__ v16, const float* __restrict__ w,
                           const float* __restrict__ bias, __half* __restrict__ y16) {
    int c = blockIdx.x * 256 + threadIdx.x;  // 0..767
    int p = blockIdx.y;                      // 0..783
    int b = blockIdx.z;                      // 0..63
    int h = c >> 6, d = c & 63;
    int y = p / WIN, x = p % WIN;
    const __half* vb = v16 + ((size_t)(b * NHEAD + h) * NTOK) * HDIM + d;
    float acc = bias[c];
#pragma unroll
    for (int ky = 0; ky < 3; ++ky) {
        int yy = y + ky - 1;
        if (yy < 0 || yy >= WIN) continue;
#pragma unroll
        for (int kx = 0; kx < 3; ++kx) {
            int xx = x + kx - 1;
            if (xx < 0 || xx >= WIN) continue;
            int nn = 1 + yy * WIN + xx;
            acc += __half2float(vb[(size_t)nn * HDIM]) * w[(ky * 3 + kx) * CDIM + c];
        }
    }
    size_t yi = ((size_t)b * NTOK + 1 + p) * CDIM + c;
    y16[yi] = __float2half(__half2float(y16[yi]) + acc);
}

// ---------------- launch ---------------------------------------------------
extern "C" void kernel_launch(void* const* d_in, const int* in_sizes, int n_in,
                              void* d_out, int out_size, void* d_ws, size_t ws_size,
                              hipStream_t stream) {
    const float* x      = (const float*)d_in[0];
    const float* w_qkv  = (const float*)d_in[1];
    const float* w_proj = (const float*)d_in[2];
    const float* b_proj = (const float*)d_in[3];
    const float* dwc_w  = (const float*)d_in[4];
    const float* dwc_b  = (const float*)d_in[5];
    const float* an     = (const float*)d_in[6];
    const float* ah     = (const float*)d_in[7];
    const float* aw     = (const float*)d_in[8];
    const float* na     = (const float*)d_in[9];
    const float* ha     = (const float*)d_in[10];
    const float* wa     = (const float*)d_in[11];
    const float* ac     = (const float*)d_in[12];
    const float* ca     = (const float*)d_in[13];
    float* out = (float*)d_out;

    char* ws = (char*)d_ws;
    __half* q16 = (__half*)(ws + OFF_Q);
    __half* k16 = (__half*)(ws + OFF_K);
    __half* v16 = (__half*)(ws + OFF_V);
    __half* y16 = (__half*)(ws + OFF_Y);
    float* agent  = (float*)(ws + OFF_AG);
    float* agentv = (float*)(ws + OFF_AV);
    float* bias1  = (float*)(ws + OFF_B1);
    float* bias2  = (float*)(ws + OFF_B2);

    // 1. biases (both stages)
    bias_kernel<<<(NHEAD * ANUM * NTOK + 255) / 256, 256, 0, stream>>>(
        an, ah, aw, ac, na, ha, wa, ca, bias1, bias2);

    // 2. qkv GEMM -> q16/k16/v16 (head-major)
    gemm_qkv<<<dim3((MROWS + 127) / 128, (3 * CDIM) / 128), 256, 0, stream>>>(
        x, w_qkv, q16, k16, v16);

    // 3. agent pooling
    pool_kernel<<<BATCH * NHEAD * ANUM, 64, 0, stream>>>(q16, agent);

    // 4. stage 1 attention -> agentv
    stage1_kernel<<<BATCH * NHEAD * ANUM, 256, 0, stream>>>(k16, v16, agent, bias1, agentv);

    // 5. stage 2 attention -> y16
    stage2_kernel<<<(BATCH * NHEAD * NTOK) / 4, 256, 0, stream>>>(q16, agent, agentv, bias2, y16);

    // 6. depthwise conv added into y16
    dwc_kernel<<<dim3(CDIM / 256, WIN * WIN, BATCH), 256, 0, stream>>>(v16, dwc_w, dwc_b, y16);

    // 7. output projection
    gemm_proj<<<dim3((MROWS + 127) / 128, CDIM / 128), 256, 0, stream>>>(y16, w_proj, b_proj, out);
}

// Round 2
// 3748.778 us; speedup vs baseline: 2.0543x; 2.0543x over previous
//
#include <hip/hip_runtime.h>
#include <hip/hip_fp16.h>

typedef _Float16 f16;
typedef _Float16 f16x8 __attribute__((ext_vector_type(8)));
typedef _Float16 f16x4 __attribute__((ext_vector_type(4)));
typedef float f32x4 __attribute__((ext_vector_type(4)));

// Problem constants
#define BATCH 64
#define NTOK 785          // 1 + 28*28
#define CDIM 768
#define NHEAD 12
#define HDIM 64
#define ANUM 49
#define WIN 28
#define MROWS (BATCH * NTOK)   // 50240

// ---------------- workspace layout (bytes) ----------------
#define SZ_Q   77168640ULL                 // (B*H*N*64) halves
#define OFF_Q  0ULL
#define OFF_K  (OFF_Q + SZ_Q)
#define OFF_V  (OFF_K + SZ_Q)
#define OFF_Y  (OFF_V + SZ_Q)
#define OFF_VT (OFF_Y + SZ_Q)              // V transposed: (bh, d=64, n=800) f16
#define SZ_VT  78643200ULL
#define OFF_P  (OFF_VT + SZ_VT)            // shared P1 (bh,64,800) / P2 (bh,800,64) f16
#define SZ_P   78643200ULL
#define OFF_AG (OFF_P + SZ_P)              // agent16: (bh, 64, 64) f16, scaled by 0.125
#define SZ_AG  6291456ULL
#define OFF_AVT (OFF_AG + SZ_AG)           // agentv^T: (bh, d=64, a=64) f16
#define OFF_B1 (OFF_AVT + SZ_AG)
#define SZ_B   1846320ULL
#define OFF_B2 (OFF_B1 + SZ_B)
// total ~482 MB

// ---------------- bilinear (jax.image.resize, half-pixel centers, 7->28) ----
__device__ __forceinline__ float bilin7(const float* __restrict__ t, int y, int x) {
    float fy = 0.25f * (float)y - 0.375f;
    float fx = 0.25f * (float)x - 0.375f;
    int y0 = (int)floorf(fy);
    int x0 = (int)floorf(fx);
    float wy = fy - (float)y0, wx = fx - (float)x0;
    int y0c = max(0, min(6, y0)),     y1c = max(0, min(6, y0 + 1));
    int x0c = max(0, min(6, x0)),     x1c = max(0, min(6, x0 + 1));
    float v00 = t[y0c * 7 + x0c], v01 = t[y0c * 7 + x1c];
    float v10 = t[y1c * 7 + x0c], v11 = t[y1c * 7 + x1c];
    return (1.f - wy) * ((1.f - wx) * v00 + wx * v01) +
           wy        * ((1.f - wx) * v10 + wx * v11);
}

// ---------------- bias kernel: builds bias1[h][a][n] and bias2[h][n][a] -----
__global__ void bias_kernel(const float* __restrict__ an, const float* __restrict__ ah,
                            const float* __restrict__ aw, const float* __restrict__ ac,
                            const float* __restrict__ na, const float* __restrict__ ha,
                            const float* __restrict__ wa, const float* __restrict__ ca,
                            float* __restrict__ bias1, float* __restrict__ bias2) {
    int idx = blockIdx.x * 256 + threadIdx.x;
    const int total = NHEAD * ANUM * NTOK;
    if (idx >= total) return;
    int h = idx / (ANUM * NTOK);
    int r = idx % (ANUM * NTOK);
    int a = r / NTOK;
    int n = r % NTOK;
    float v1, v2;
    if (n == 0) {
        v1 = ac[h * ANUM + a];
        v2 = ca[h * ANUM + a];
    } else {
        int p = n - 1, y = p / WIN, x = p % WIN;
        int haidx = h * ANUM + a;
        v1 = bilin7(an + haidx * 49, y, x) + ah[haidx * WIN + y] + aw[haidx * WIN + x];
        v2 = bilin7(na + haidx * 49, y, x) + ha[(h * WIN + y) * ANUM + a] + wa[(h * WIN + x) * ANUM + a];
    }
    bias1[(h * ANUM + a) * NTOK + n] = v1;
    bias2[((size_t)h * NTOK + n) * ANUM + a] = v2;
}

// ---------------- qkv GEMM: out = x @ w_qkv^T, scattered fp16 store ---------
__global__ __launch_bounds__(256) void gemm_qkv(const float* __restrict__ A,
                                                const float* __restrict__ W,
                                                f16* __restrict__ qo,
                                                f16* __restrict__ ko,
                                                f16* __restrict__ vo,
                                                f16* __restrict__ vto) {
    __shared__ float As[16][132];
    __shared__ float Bs[16][132];
    const int K = CDIM;
    int tid = threadIdx.x;
    int m0 = blockIdx.x * 128;
    int n0 = blockIdx.y * 128;
    int tm = tid >> 4, tn = tid & 15;
    int lrow = tid >> 2;
    int lcol = (tid & 3) << 2;

    float acc[8][8];
#pragma unroll
    for (int i = 0; i < 8; ++i)
#pragma unroll
        for (int j = 0; j < 8; ++j) acc[i][j] = 0.f;

    int rowA2 = min(m0 + lrow + 64, MROWS - 1);
    const float* Ap  = A + (size_t)(m0 + lrow) * K + lcol;
    const float* Ap2 = A + (size_t)rowA2 * K + lcol;
    const float* Bp  = W + (size_t)(n0 + lrow) * K + lcol;
    const float* Bp2 = W + (size_t)(n0 + lrow + 64) * K + lcol;

    for (int k0 = 0; k0 < K; k0 += 16) {
        float4 a0 = *(const float4*)(Ap + k0);
        float4 a1 = *(const float4*)(Ap2 + k0);
        float4 b0 = *(const float4*)(Bp + k0);
        float4 b1 = *(const float4*)(Bp2 + k0);
        __syncthreads();
        As[lcol + 0][lrow] = a0.x; As[lcol + 1][lrow] = a0.y;
        As[lcol + 2][lrow] = a0.z; As[lcol + 3][lrow] = a0.w;
        As[lcol + 0][lrow + 64] = a1.x; As[lcol + 1][lrow + 64] = a1.y;
        As[lcol + 2][lrow + 64] = a1.z; As[lcol + 3][lrow + 64] = a1.w;
        Bs[lcol + 0][lrow] = b0.x; Bs[lcol + 1][lrow] = b0.y;
        Bs[lcol + 2][lrow] = b0.z; Bs[lcol + 3][lrow] = b0.w;
        Bs[lcol + 0][lrow + 64] = b1.x; Bs[lcol + 1][lrow + 64] = b1.y;
        Bs[lcol + 2][lrow + 64] = b1.z; Bs[lcol + 3][lrow + 64] = b1.w;
        __syncthreads();
#pragma unroll
        for (int kk = 0; kk < 16; ++kk) {
            float av[8], bv[8];
            *(float4*)&av[0] = *(const float4*)&As[kk][tm * 4];
            *(float4*)&av[4] = *(const float4*)&As[kk][64 + tm * 4];
            *(float4*)&bv[0] = *(const float4*)&Bs[kk][tn * 4];
            *(float4*)&bv[4] = *(const float4*)&Bs[kk][64 + tn * 4];
#pragma unroll
            for (int i = 0; i < 8; ++i)
#pragma unroll
                for (int j = 0; j < 8; ++j)
                    acc[i][j] = fmaf(av[i], bv[j], acc[i][j]);
        }
    }

    int t = n0 / CDIM;
    f16* Ob = (t == 0) ? qo : (t == 1) ? ko : vo;
    int h0 = (n0 % CDIM) >> 6;
#pragma unroll
    for (int rh = 0; rh < 2; ++rh) {
#pragma unroll
        for (int i = 0; i < 4; ++i) {
            int row = m0 + rh * 64 + tm * 4 + i;
            if (row < MROWS) {
                int bb = row / NTOK;
                int nn = row - bb * NTOK;
                size_t base = (((size_t)bb * NHEAD + h0) * NTOK + nn) * HDIM + tn * 4;
                f16* p0 = Ob + base;
                f16* p1 = Ob + base + (size_t)NTOK * HDIM;  // h0+1
#pragma unroll
                for (int j = 0; j < 4; ++j) {
                    f16 v0 = (f16)acc[rh * 4 + i][j];
                    f16 v1 = (f16)acc[rh * 4 + i][4 + j];
                    p0[j] = v0;
                    p1[j] = v1;
                    if (t == 2) {
                        vto[(((size_t)bb * NHEAD + h0) * HDIM + tn * 4 + j) * 800 + nn] = v0;
                        vto[(((size_t)bb * NHEAD + h0 + 1) * HDIM + tn * 4 + j) * 800 + nn] = v1;
                    }
                }
            }
        }
    }
}

// ---------------- proj GEMM: d_out = y @ w_proj^T + b ----------------------
__global__ __launch_bounds__(256) void gemm_proj(const f16* __restrict__ Y,
                                                 const float* __restrict__ W,
                                                 const float* __restrict__ bias,
                                                 float* __restrict__ D) {
    __shared__ float As[16][132];
    __shared__ float Bs[16][132];
    const int K = CDIM;
    int tid = threadIdx.x;
    int m0 = blockIdx.x * 128;
    int n0 = blockIdx.y * 128;
    int tm = tid >> 4, tn = tid & 15;
    int lrow = tid >> 2;
    int lcol = (tid & 3) << 2;

    float acc[8][8];
#pragma unroll
    for (int i = 0; i < 8; ++i)
#pragma unroll
        for (int j = 0; j < 8; ++j) acc[i][j] = 0.f;

    int rowA2 = min(m0 + lrow + 64, MROWS - 1);
    const f16* Ap  = Y + (size_t)(m0 + lrow) * K + lcol;
    const f16* Ap2 = Y + (size_t)rowA2 * K + lcol;
    const float* Bp  = W + (size_t)(n0 + lrow) * K + lcol;
    const float* Bp2 = W + (size_t)(n0 + lrow + 64) * K + lcol;

    for (int k0 = 0; k0 < K; k0 += 16) {
        f16x4 ra0 = *(const f16x4*)(Ap + k0);
        f16x4 ra1 = *(const f16x4*)(Ap2 + k0);
        float4 b0 = *(const float4*)(Bp + k0);
        float4 b1 = *(const float4*)(Bp2 + k0);
        __syncthreads();
        As[lcol + 0][lrow] = (float)ra0[0]; As[lcol + 1][lrow] = (float)ra0[1];
        As[lcol + 2][lrow] = (float)ra0[2]; As[lcol + 3][lrow] = (float)ra0[3];
        As[lcol + 0][lrow + 64] = (float)ra1[0]; As[lcol + 1][lrow + 64] = (float)ra1[1];
        As[lcol + 2][lrow + 64] = (float)ra1[2]; As[lcol + 3][lrow + 64] = (float)ra1[3];
        Bs[lcol + 0][lrow] = b0.x; Bs[lcol + 1][lrow] = b0.y;
        Bs[lcol + 2][lrow] = b0.z; Bs[lcol + 3][lrow] = b0.w;
        Bs[lcol + 0][lrow + 64] = b1.x; Bs[lcol + 1][lrow + 64] = b1.y;
        Bs[lcol + 2][lrow + 64] = b1.z; Bs[lcol + 3][lrow + 64] = b1.w;
        __syncthreads();
#pragma unroll
        for (int kk = 0; kk < 16; ++kk) {
            float av[8], bv[8];
            *(float4*)&av[0] = *(const float4*)&As[kk][tm * 4];
            *(float4*)&av[4] = *(const float4*)&As[kk][64 + tm * 4];
            *(float4*)&bv[0] = *(const float4*)&Bs[kk][tn * 4];
            *(float4*)&bv[4] = *(const float4*)&Bs[kk][64 + tn * 4];
#pragma unroll
            for (int i = 0; i < 8; ++i)
#pragma unroll
                for (int j = 0; j < 8; ++j)
                    acc[i][j] = fmaf(av[i], bv[j], acc[i][j]);
        }
    }

    float bs0[4], bs1[4];
#pragma unroll
    for (int j = 0; j < 4; ++j) {
        bs0[j] = bias[n0 + tn * 4 + j];
        bs1[j] = bias[n0 + 64 + tn * 4 + j];
    }
#pragma unroll
    for (int rh = 0; rh < 2; ++rh) {
#pragma unroll
        for (int i = 0; i < 4; ++i) {
            int row = m0 + rh * 64 + tm * 4 + i;
            if (row < MROWS) {
                float* dp = D + (size_t)row * CDIM + n0 + tn * 4;
                float4 o0, o1;
                o0.x = acc[rh * 4 + i][0] + bs0[0]; o0.y = acc[rh * 4 + i][1] + bs0[1];
                o0.z = acc[rh * 4 + i][2] + bs0[2]; o0.w = acc[rh * 4 + i][3] + bs0[3];
                o1.x = acc[rh * 4 + i][4] + bs1[0]; o1.y = acc[rh * 4 + i][5] + bs1[1];
                o1.z = acc[rh * 4 + i][6] + bs1[2]; o1.w = acc[rh * 4 + i][7] + bs1[3];
                *(float4*)dp = o0;
                *(float4*)(dp + 64) = o1;
            }
        }
    }
}

// ---------------- agent pooling -> agent16 (f16, pre-scaled by 0.125) ------
__global__ void pool_kernel(const f16* __restrict__ q16, f16* __restrict__ agent16) {
    int bidx = blockIdx.x;           // (b, h, a)
    int d = threadIdx.x;             // 64 threads
    int b = bidx / (NHEAD * ANUM);
    int r = bidx % (NHEAD * ANUM);
    int h = r / ANUM;
    int a = r % ANUM;
    int py = a / 7, px = a % 7;
    const f16* base = q16 + ((size_t)(b * NHEAD + h) * NTOK) * HDIM;
    float s = 0.f;
#pragma unroll
    for (int dy = 0; dy < 4; ++dy)
#pragma unroll
        for (int dx = 0; dx < 4; ++dx) {
            int n = 1 + (py * 4 + dy) * WIN + (px * 4 + dx);
            s += (float)base[(size_t)n * HDIM + d];
        }
    agent16[((size_t)(b * NHEAD + h) * 64 + a) * 64 + d] = (f16)(s * (1.0f / 16.0f) * 0.125f);
}

// ---------------- stage1 scores: S1 = agent16 . K^T + bias1 -> P (f16) -----
// P layout: (bh, a=64, n=800). MFMA 16x16x32 f16.
// A-frag: lane holds A[m=lane&15][k=quad*8+j]; B-frag: B[k=quad*8+j][n=lane&15]
// C/D: lane holds C[m=quad*4+r][n=lane&15]
__global__ __launch_bounds__(256) void s1_score(const f16* __restrict__ k16,
                                                const f16* __restrict__ agent16,
                                                const float* __restrict__ bias1,
                                                f16* __restrict__ P) {
    int bh = blockIdx.x;
    int h = bh % NHEAD;
    int wid = threadIdx.x >> 6;
    int lane = threadIdx.x & 63;
    int quad = lane >> 4, col = lane & 15;
    const f16* ag = agent16 + (size_t)bh * 4096;
    f16x8 afr[4][2];
#pragma unroll
    for (int mt = 0; mt < 4; ++mt)
#pragma unroll
        for (int ks = 0; ks < 2; ++ks)
            afr[mt][ks] = *(const f16x8*)(ag + (mt * 16 + col) * 64 + ks * 32 + quad * 8);
    const f16* kb = k16 + (size_t)bh * (NTOK * HDIM);
    f16* Pb = P + (size_t)bh * (64 * 800);
    for (int nt = wid; nt < 50; nt += 4) {
        int nn = nt * 16 + col;
        // reads for nn>=785 run (in-bounds of ws) into next region; masked later
        f16x8 b0 = *(const f16x8*)(kb + (size_t)nn * 64 + quad * 8);
        f16x8 b1 = *(const f16x8*)(kb + (size_t)nn * 64 + 32 + quad * 8);
#pragma unroll
        for (int mt = 0; mt < 4; ++mt) {
            f32x4 c = {0.f, 0.f, 0.f, 0.f};
            c = __builtin_amdgcn_mfma_f32_16x16x32_f16(afr[mt][0], b0, c, 0, 0, 0);
            c = __builtin_amdgcn_mfma_f32_16x16x32_f16(afr[mt][1], b1, c, 0, 0, 0);
#pragma unroll
            for (int r = 0; r < 4; ++r) {
                int a = mt * 16 + quad * 4 + r;
                float v = c[r];
                if (a < ANUM && nn < NTOK) v += bias1[(h * ANUM + a) * NTOK + nn];
                Pb[(size_t)a * 800 + nn] = (f16)v;
            }
        }
    }
}

// ---------------- generic in-place row softmax over f16 buffer -------------
// row r: bh = r / rpb_valid, i = r % rpb_valid; ptr = buf + (bh*rpb_alloc+i)*stride
// softmax over [0, valid); zero-fill [valid, stride)
__global__ __launch_bounds__(256) void softmax16(f16* __restrict__ buf, int total_rows,
                                                 int rpb_valid, int rpb_alloc,
                                                 int valid, int stride) {
    int wid = threadIdx.x >> 6, lane = threadIdx.x & 63;
    int r = blockIdx.x * 4 + wid;
    if (r >= total_rows) return;
    int bh = r / rpb_valid, i0 = r % rpb_valid;
    f16* p = buf + ((size_t)bh * rpb_alloc + i0) * stride;
    float m = -1e30f;
    for (int i = lane; i < valid; i += 64) m = fmaxf(m, (float)p[i]);
#pragma unroll
    for (int off = 32; off > 0; off >>= 1) m = fmaxf(m, __shfl_xor(m, off));
    float s = 0.f;
    for (int i = lane; i < valid; i += 64) s += __expf((float)p[i] - m);
#pragma unroll
    for (int off = 32; off > 0; off >>= 1) s += __shfl_xor(s, off);
    float inv = 1.0f / s;
    for (int i = lane; i < stride; i += 64) {
        float v = (i < valid) ? __expf((float)p[i] - m) * inv : 0.f;
        p[i] = (f16)v;
    }
}

// ---------------- stage1 PV: agentv^T = (P1 . V)^T ------------------------
__global__ __launch_bounds__(256) void s1_pv(const f16* __restrict__ P,
                                             const f16* __restrict__ vT,
                                             f16* __restrict__ avT) {
    int bh = blockIdx.x;
    int wid = threadIdx.x >> 6;
    int lane = threadIdx.x & 63;
    int quad = lane >> 4, col = lane & 15;
    const f16* Pb = P + (size_t)bh * 51200;
    const f16* Vt = vT + (size_t)bh * 51200;
    int m0 = wid * 16;
    f32x4 acc0 = {0.f, 0.f, 0.f, 0.f}, acc1 = acc0, acc2 = acc0, acc3 = acc0;
    for (int ks = 0; ks < 25; ++ks) {
        int k0 = ks * 32 + quad * 8;
        f16x8 a  = *(const f16x8*)(Pb + (size_t)(m0 + col) * 800 + k0);
        f16x8 b0 = *(const f16x8*)(Vt + (size_t)(col) * 800 + k0);
        f16x8 b1 = *(const f16x8*)(Vt + (size_t)(16 + col) * 800 + k0);
        f16x8 b2 = *(const f16x8*)(Vt + (size_t)(32 + col) * 800 + k0);
        f16x8 b3 = *(const f16x8*)(Vt + (size_t)(48 + col) * 800 + k0);
        acc0 = __builtin_amdgcn_mfma_f32_16x16x32_f16(a, b0, acc0, 0, 0, 0);
        acc1 = __builtin_amdgcn_mfma_f32_16x16x32_f16(a, b1, acc1, 0, 0, 0);
        acc2 = __builtin_amdgcn_mfma_f32_16x16x32_f16(a, b2, acc2, 0, 0, 0);
        acc3 = __builtin_amdgcn_mfma_f32_16x16x32_f16(a, b3, acc3, 0, 0, 0);
    }
    f16* av = avT + (size_t)bh * 4096;
#pragma unroll
    for (int dt = 0; dt < 4; ++dt) {
        f32x4 acc = (dt == 0) ? acc0 : (dt == 1) ? acc1 : (dt == 2) ? acc2 : acc3;
        f16x4 o;
#pragma unroll
        for (int r = 0; r < 4; ++r) o[r] = (f16)acc[r];
        *(f16x4*)(av + (size_t)(dt * 16 + col) * 64 + m0 + quad * 4) = o;
    }
}

// ---------------- stage2 scores: S2 = q . agent16^T + bias2 -> P (f16) -----
// P layout: (bh, n=800, a=64)
__global__ __launch_bounds__(256) void s2_score(const f16* __restrict__ q16,
                                                const f16* __restrict__ agent16,
                                                const float* __restrict__ bias2,
                                                f16* __restrict__ P) {
    int bh = blockIdx.x;
    int h = bh % NHEAD;
    int wid = threadIdx.x >> 6, lane = threadIdx.x & 63;
    int quad = lane >> 4, col = lane & 15;
    int qt = blockIdx.y * 4 + wid;
    if (qt >= 50) return;
    int n0 = qt * 16;
    const f16* qb = q16 + (size_t)bh * (NTOK * HDIM);
    f16x8 a0 = *(const f16x8*)(qb + (size_t)(n0 + col) * 64 + quad * 8);
    f16x8 a1 = *(const f16x8*)(qb + (size_t)(n0 + col) * 64 + 32 + quad * 8);
    const f16* ag = agent16 + (size_t)bh * 4096;
    f16* Pb = P + (size_t)bh * 51200;
#pragma unroll
    for (int at = 0; at < 4; ++at) {
        f16x8 b0 = *(const f16x8*)(ag + (at * 16 + col) * 64 + quad * 8);
        f16x8 b1 = *(const f16x8*)(ag + (at * 16 + col) * 64 + 32 + quad * 8);
        f32x4 c = {0.f, 0.f, 0.f, 0.f};
        c = __builtin_amdgcn_mfma_f32_16x16x32_f16(a0, b0, c, 0, 0, 0);
        c = __builtin_amdgcn_mfma_f32_16x16x32_f16(a1, b1, c, 0, 0, 0);
#pragma unroll
        for (int r = 0; r < 4; ++r) {
            int n = n0 + quad * 4 + r;
            int aa = at * 16 + col;
            float v = c[r];
            if (n < NTOK && aa < ANUM) v += bias2[((size_t)h * NTOK + n) * ANUM + aa];
            Pb[(size_t)n * 64 + aa] = (f16)v;
        }
    }
}

// ---------------- stage2 out: y = P2 . agentv -----------------------------
__global__ __launch_bounds__(256) void s2_out(const f16* __restrict__ P,
                                              const f16* __restrict__ avT,
                                              f16* __restrict__ y16) {
    int bh = blockIdx.x;
    int b = bh / NHEAD, h = bh % NHEAD;
    int wid = threadIdx.x >> 6, lane = threadIdx.x & 63;
    int quad = lane >> 4, col = lane & 15;
    int qt = blockIdx.y * 4 + wid;
    if (qt >= 50) return;
    int n0 = qt * 16;
    const f16* Pb = P + (size_t)bh * 51200;
    f16x8 a0 = *(const f16x8*)(Pb + (size_t)(n0 + col) * 64 + quad * 8);
    f16x8 a1 = *(const f16x8*)(Pb + (size_t)(n0 + col) * 64 + 32 + quad * 8);
    const f16* av = avT + (size_t)bh * 4096;
#pragma unroll
    for (int dt = 0; dt < 4; ++dt) {
        f16x8 b0 = *(const f16x8*)(av + (dt * 16 + col) * 64 + quad * 8);
        f16x8 b1 = *(const f16x8*)(av + (dt * 16 + col) * 64 + 32 + quad * 8);
        f32x4 c = {0.f, 0.f, 0.f, 0.f};
        c = __builtin_amdgcn_mfma_f32_16x16x32_f16(a0, b0, c, 0, 0, 0);
        c = __builtin_amdgcn_mfma_f32_16x16x32_f16(a1, b1, c, 0, 0, 0);
#pragma unroll
        for (int r = 0; r < 4; ++r) {
            int n = n0 + quad * 4 + r;
            if (n < NTOK)
                y16[((size_t)b * NTOK + n) * CDIM + h * HDIM + dt * 16 + col] = (f16)c[r];
        }
    }
}

// ---------------- depthwise 3x3 conv on V image tokens, add into y ---------
__global__ void dwc_kernel(const f16* __restrict__ v16, const float* __restrict__ w,
                           const float* __restrict__ bias, f16* __restrict__ y16) {
    int c = blockIdx.x * 256 + threadIdx.x;  // 0..767
    int p = blockIdx.y;                      // 0..783
    int b = blockIdx.z;                      // 0..63
    int h = c >> 6, d = c & 63;
    int y = p / WIN, x = p % WIN;
    const f16* vb = v16 + ((size_t)(b * NHEAD + h) * NTOK) * HDIM + d;
    float acc = bias[c];
#pragma unroll
    for (int ky = 0; ky < 3; ++ky) {
        int yy = y + ky - 1;
        if (yy < 0 || yy >= WIN) continue;
#pragma unroll
        for (int kx = 0; kx < 3; ++kx) {
            int xx = x + kx - 1;
            if (xx < 0 || xx >= WIN) continue;
            int nn = 1 + yy * WIN + xx;
            acc += (float)vb[(size_t)nn * HDIM] * w[(ky * 3 + kx) * CDIM + c];
        }
    }
    size_t yi = ((size_t)b * NTOK + 1 + p) * CDIM + c;
    y16[yi] = (f16)((float)y16[yi] + acc);
}

// ---------------- launch ---------------------------------------------------
extern "C" void kernel_launch(void* const* d_in, const int* in_sizes, int n_in,
                              void* d_out, int out_size, void* d_ws, size_t ws_size,
                              hipStream_t stream) {
    const float* x      = (const float*)d_in[0];
    const float* w_qkv  = (const float*)d_in[1];
    const float* w_proj = (const float*)d_in[2];
    const float* b_proj = (const float*)d_in[3];
    const float* dwc_w  = (const float*)d_in[4];
    const float* dwc_b  = (const float*)d_in[5];
    const float* an     = (const float*)d_in[6];
    const float* ah     = (const float*)d_in[7];
    const float* aw     = (const float*)d_in[8];
    const float* na     = (const float*)d_in[9];
    const float* ha     = (const float*)d_in[10];
    const float* wa     = (const float*)d_in[11];
    const float* ac     = (const float*)d_in[12];
    const float* ca     = (const float*)d_in[13];
    float* out = (float*)d_out;

    char* ws = (char*)d_ws;
    f16* q16   = (f16*)(ws + OFF_Q);
    f16* k16   = (f16*)(ws + OFF_K);
    f16* v16   = (f16*)(ws + OFF_V);
    f16* y16   = (f16*)(ws + OFF_Y);
    f16* vT    = (f16*)(ws + OFF_VT);
    f16* Pbuf  = (f16*)(ws + OFF_P);
    f16* agent16 = (f16*)(ws + OFF_AG);
    f16* avT   = (f16*)(ws + OFF_AVT);
    float* bias1 = (float*)(ws + OFF_B1);
    float* bias2 = (float*)(ws + OFF_B2);

    bias_kernel<<<(NHEAD * ANUM * NTOK + 255) / 256, 256, 0, stream>>>(
        an, ah, aw, ac, na, ha, wa, ca, bias1, bias2);

    gemm_qkv<<<dim3((MROWS + 127) / 128, (3 * CDIM) / 128), 256, 0, stream>>>(
        x, w_qkv, q16, k16, v16, vT);

    pool_kernel<<<BATCH * NHEAD * ANUM, 64, 0, stream>>>(q16, agent16);

    // stage 1: scores -> softmax (in place) -> PV
    s1_score<<<BATCH * NHEAD, 256, 0, stream>>>(k16, agent16, bias1, Pbuf);
    softmax16<<<(BATCH * NHEAD * ANUM + 3) / 4, 256, 0, stream>>>(
        Pbuf, BATCH * NHEAD * ANUM, ANUM, 64, NTOK, 800);
    s1_pv<<<BATCH * NHEAD, 256, 0, stream>>>(Pbuf, vT, avT);

    // stage 2: scores -> softmax (in place) -> out (reuses Pbuf)
    s2_score<<<dim3(BATCH * NHEAD, 13), 256, 0, stream>>>(q16, agent16, bias2, Pbuf);
    softmax16<<<(BATCH * NHEAD * NTOK + 3) / 4, 256, 0, stream>>>(
        Pbuf, BATCH * NHEAD * NTOK, NTOK, 800, ANUM, 64);
    s2_out<<<dim3(BATCH * NHEAD, 13), 256, 0, stream>>>(Pbuf, avT, y16);

    dwc_kernel<<<dim3(CDIM / 256, WIN * WIN, BATCH), 256, 0, stream>>>(v16, dwc_w, dwc_b, y16);

    gemm_proj<<<dim3((MROWS + 127) / 128, CDIM / 128), 256, 0, stream>>>(y16, w_proj, b_proj, out);
}

// Round 3
// 1490.553 us; speedup vs baseline: 5.1666x; 2.5150x over previous
//
#include <hip/hip_runtime.h>
#include <hip/hip_fp16.h>

typedef _Float16 f16;
typedef _Float16 f16x8 __attribute__((ext_vector_type(8)));
typedef _Float16 f16x4 __attribute__((ext_vector_type(4)));
typedef float f32x4 __attribute__((ext_vector_type(4)));

// Problem constants
#define BATCH 64
#define NTOK 785          // 1 + 28*28
#define CDIM 768
#define NHEAD 12
#define HDIM 64
#define ANUM 49
#define WIN 28
#define MROWS (BATCH * NTOK)   // 50240

// ---------------- workspace layout (bytes) ----------------
#define SZ_Q   77168640ULL                 // (B*H*N*64) halves
#define OFF_Q  0ULL
#define OFF_K  (OFF_Q + SZ_Q)
#define OFF_V  (OFF_K + SZ_Q)
#define OFF_Y  (OFF_V + SZ_Q)
#define OFF_VT (OFF_Y + SZ_Q)              // V transposed: (bh, d=64, n=800) f16
#define SZ_VT  78643200ULL
#define OFF_P  (OFF_VT + SZ_VT)            // P1 (bh,64,800) / P2 (bh,800,64) f16; also X16 / WP16 overlay
#define SZ_P   78643200ULL
#define OFF_AG (OFF_P + SZ_P)              // agent16: (bh, 64, 64) f16, scaled by 0.125
#define SZ_AG  6291456ULL
#define OFF_AVT (OFF_AG + SZ_AG)           // agentv^T: (bh, d=64, a=64) f16; also W16 overlay
#define OFF_B1 (OFF_AVT + SZ_AG)
#define SZ_B   1846320ULL
#define OFF_B2 (OFF_B1 + SZ_B)
// total ~482 MB (overlays add nothing)

#define GLL(g, l) __builtin_amdgcn_global_load_lds( \
    (const __attribute__((address_space(1))) void*)(g), \
    (__attribute__((address_space(3))) void*)(l), 16, 0, 0)

// ---------------- fp32 -> fp16 conversion (x4 vectorized) -------------------
__global__ void cvt_kernel(const float* __restrict__ s, f16* __restrict__ d, int n4) {
    int i = blockIdx.x * 256 + threadIdx.x;
    if (i >= n4) return;
    float4 v = ((const float4*)s)[i];
    f16x4 o = {(f16)v.x, (f16)v.y, (f16)v.z, (f16)v.w};
    ((f16x4*)d)[i] = o;
}

// ---------------- bilinear (jax.image.resize, half-pixel centers, 7->28) ----
__device__ __forceinline__ float bilin7(const float* __restrict__ t, int y, int x) {
    float fy = 0.25f * (float)y - 0.375f;
    float fx = 0.25f * (float)x - 0.375f;
    int y0 = (int)floorf(fy);
    int x0 = (int)floorf(fx);
    float wy = fy - (float)y0, wx = fx - (float)x0;
    int y0c = max(0, min(6, y0)),     y1c = max(0, min(6, y0 + 1));
    int x0c = max(0, min(6, x0)),     x1c = max(0, min(6, x0 + 1));
    float v00 = t[y0c * 7 + x0c], v01 = t[y0c * 7 + x1c];
    float v10 = t[y1c * 7 + x0c], v11 = t[y1c * 7 + x1c];
    return (1.f - wy) * ((1.f - wx) * v00 + wx * v01) +
           wy        * ((1.f - wx) * v10 + wx * v11);
}

// ---------------- bias kernel: builds bias1[h][a][n] and bias2[h][n][a] -----
__global__ void bias_kernel(const float* __restrict__ an, const float* __restrict__ ah,
                            const float* __restrict__ aw, const float* __restrict__ ac,
                            const float* __restrict__ na, const float* __restrict__ ha,
                            const float* __restrict__ wa, const float* __restrict__ ca,
                            float* __restrict__ bias1, float* __restrict__ bias2) {
    int idx = blockIdx.x * 256 + threadIdx.x;
    const int total = NHEAD * ANUM * NTOK;
    if (idx >= total) return;
    int h = idx / (ANUM * NTOK);
    int r = idx % (ANUM * NTOK);
    int a = r / NTOK;
    int n = r % NTOK;
    float v1, v2;
    if (n == 0) {
        v1 = ac[h * ANUM + a];
        v2 = ca[h * ANUM + a];
    } else {
        int p = n - 1, y = p / WIN, x = p % WIN;
        int haidx = h * ANUM + a;
        v1 = bilin7(an + haidx * 49, y, x) + ah[haidx * WIN + y] + aw[haidx * WIN + x];
        v2 = bilin7(na + haidx * 49, y, x) + ha[(h * WIN + y) * ANUM + a] + wa[(h * WIN + x) * ANUM + a];
    }
    bias1[(h * ANUM + a) * NTOK + n] = v1;
    bias2[((size_t)h * NTOK + n) * ANUM + a] = v2;
}

// ---------------- MFMA qkv GEMM: C = X16 @ W16^T, scatter f16 store --------
// A: (M,768) f16, B: (2304,768) f16. 128x128 tile, BK=32, 2x2 waves of 64x64.
__global__ __launch_bounds__(256) void mfma_qkv(const f16* __restrict__ A,
                                                const f16* __restrict__ B,
                                                f16* __restrict__ qo,
                                                f16* __restrict__ ko,
                                                f16* __restrict__ vo,
                                                f16* __restrict__ vto) {
    __shared__ f16 As[128 * 32];
    __shared__ f16 Bs[128 * 32];
    const int K = CDIM;
    int tid = threadIdx.x, wave = tid >> 6, lane = tid & 63;
    int quad = lane >> 4, col = lane & 15;
    int m0 = blockIdx.x * 128, n0 = blockIdx.y * 128;
    int wm = wave >> 1, wn = wave & 1;

    int srow = wave * 16 + (lane >> 2);
    int skc  = (lane & 3) * 8;
    int ar0 = min(m0 + srow, MROWS - 1);
    int ar1 = min(m0 + srow + 64, MROWS - 1);
    const f16* agp0 = A + (size_t)ar0 * K + skc;
    const f16* agp1 = A + (size_t)ar1 * K + skc;
    const f16* bgp0 = B + (size_t)(n0 + srow) * K + skc;
    const f16* bgp1 = B + (size_t)(n0 + srow + 64) * K + skc;
    f16* alds0 = As + wave * 512;
    f16* alds1 = As + 2048 + wave * 512;
    f16* blds0 = Bs + wave * 512;
    f16* blds1 = Bs + 2048 + wave * 512;

    f32x4 acc[4][4];
#pragma unroll
    for (int i = 0; i < 4; ++i)
#pragma unroll
        for (int j = 0; j < 4; ++j) acc[i][j] = (f32x4){0.f, 0.f, 0.f, 0.f};

    for (int k0 = 0; k0 < K; k0 += 32) {
        GLL(agp0 + k0, alds0);
        GLL(agp1 + k0, alds1);
        GLL(bgp0 + k0, blds0);
        GLL(bgp1 + k0, blds1);
        __syncthreads();
        f16x8 af[4], bf[4];
#pragma unroll
        for (int mt = 0; mt < 4; ++mt)
            af[mt] = *(const f16x8*)&As[(wm * 64 + mt * 16 + col) * 32 + quad * 8];
#pragma unroll
        for (int nt = 0; nt < 4; ++nt)
            bf[nt] = *(const f16x8*)&Bs[(wn * 64 + nt * 16 + col) * 32 + quad * 8];
#pragma unroll
        for (int mt = 0; mt < 4; ++mt)
#pragma unroll
            for (int nt = 0; nt < 4; ++nt)
                acc[mt][nt] = __builtin_amdgcn_mfma_f32_16x16x32_f16(af[mt], bf[nt], acc[mt][nt], 0, 0, 0);
        __syncthreads();
    }

    int nbase = n0 + wn * 64;
    int t = nbase / CDIM;
    int h = (nbase % CDIM) >> 6;
    f16* Ob = (t == 0) ? qo : (t == 1) ? ko : vo;
#pragma unroll
    for (int mt = 0; mt < 4; ++mt) {
#pragma unroll
        for (int r = 0; r < 4; ++r) {
            int m = m0 + wm * 64 + mt * 16 + quad * 4 + r;
            if (m < MROWS) {
                int bb = m / NTOK, nn = m - bb * NTOK;
                size_t obase = (((size_t)bb * NHEAD + h) * NTOK + nn) * HDIM;
#pragma unroll
                for (int nt = 0; nt < 4; ++nt) {
                    f16 v = (f16)acc[mt][nt][r];
                    Ob[obase + nt * 16 + col] = v;
                    if (t == 2)
                        vto[(((size_t)bb * NHEAD + h) * HDIM + nt * 16 + col) * 800 + nn] = v;
                }
            }
        }
    }
}

// ---------------- MFMA proj GEMM: D = Y16 @ WP16^T + bias (fp32 out) -------
__global__ __launch_bounds__(256) void mfma_proj(const f16* __restrict__ A,
                                                 const f16* __restrict__ B,
                                                 const float* __restrict__ bias,
                                                 float* __restrict__ D) {
    __shared__ f16 As[128 * 32];
    __shared__ f16 Bs[128 * 32];
    const int K = CDIM;
    int tid = threadIdx.x, wave = tid >> 6, lane = tid & 63;
    int quad = lane >> 4, col = lane & 15;
    int m0 = blockIdx.x * 128, n0 = blockIdx.y * 128;
    int wm = wave >> 1, wn = wave & 1;

    int srow = wave * 16 + (lane >> 2);
    int skc  = (lane & 3) * 8;
    int ar0 = min(m0 + srow, MROWS - 1);
    int ar1 = min(m0 + srow + 64, MROWS - 1);
    const f16* agp0 = A + (size_t)ar0 * K + skc;
    const f16* agp1 = A + (size_t)ar1 * K + skc;
    const f16* bgp0 = B + (size_t)(n0 + srow) * K + skc;
    const f16* bgp1 = B + (size_t)(n0 + srow + 64) * K + skc;
    f16* alds0 = As + wave * 512;
    f16* alds1 = As + 2048 + wave * 512;
    f16* blds0 = Bs + wave * 512;
    f16* blds1 = Bs + 2048 + wave * 512;

    f32x4 acc[4][4];
#pragma unroll
    for (int i = 0; i < 4; ++i)
#pragma unroll
        for (int j = 0; j < 4; ++j) acc[i][j] = (f32x4){0.f, 0.f, 0.f, 0.f};

    for (int k0 = 0; k0 < K; k0 += 32) {
        GLL(agp0 + k0, alds0);
        GLL(agp1 + k0, alds1);
        GLL(bgp0 + k0, blds0);
        GLL(bgp1 + k0, blds1);
        __syncthreads();
        f16x8 af[4], bf[4];
#pragma unroll
        for (int mt = 0; mt < 4; ++mt)
            af[mt] = *(const f16x8*)&As[(wm * 64 + mt * 16 + col) * 32 + quad * 8];
#pragma unroll
        for (int nt = 0; nt < 4; ++nt)
            bf[nt] = *(const f16x8*)&Bs[(wn * 64 + nt * 16 + col) * 32 + quad * 8];
#pragma unroll
        for (int mt = 0; mt < 4; ++mt)
#pragma unroll
            for (int nt = 0; nt < 4; ++nt)
                acc[mt][nt] = __builtin_amdgcn_mfma_f32_16x16x32_f16(af[mt], bf[nt], acc[mt][nt], 0, 0, 0);
        __syncthreads();
    }

    int nb = n0 + wn * 64;
    float bv[4];
#pragma unroll
    for (int nt = 0; nt < 4; ++nt) bv[nt] = bias[nb + nt * 16 + col];
#pragma unroll
    for (int mt = 0; mt < 4; ++mt) {
#pragma unroll
        for (int r = 0; r < 4; ++r) {
            int m = m0 + wm * 64 + mt * 16 + quad * 4 + r;
            if (m < MROWS) {
                float* dp = D + (size_t)m * CDIM + nb;
#pragma unroll
                for (int nt = 0; nt < 4; ++nt)
                    dp[nt * 16 + col] = acc[mt][nt][r] + bv[nt];
            }
        }
    }
}

// ---------------- agent pooling -> agent16 (f16, pre-scaled by 0.125) ------
__global__ void pool_kernel(const f16* __restrict__ q16, f16* __restrict__ agent16) {
    int bidx = blockIdx.x;           // (b, h, a)
    int d = threadIdx.x;             // 64 threads
    int b = bidx / (NHEAD * ANUM);
    int r = bidx % (NHEAD * ANUM);
    int h = r / ANUM;
    int a = r % ANUM;
    int py = a / 7, px = a % 7;
    const f16* base = q16 + ((size_t)(b * NHEAD + h) * NTOK) * HDIM;
    float s = 0.f;
#pragma unroll
    for (int dy = 0; dy < 4; ++dy)
#pragma unroll
        for (int dx = 0; dx < 4; ++dx) {
            int n = 1 + (py * 4 + dy) * WIN + (px * 4 + dx);
            s += (float)base[(size_t)n * HDIM + d];
        }
    agent16[((size_t)(b * NHEAD + h) * 64 + a) * 64 + d] = (f16)(s * (1.0f / 16.0f) * 0.125f);
}

// ---------------- stage1 scores: S1 = agent16 . K^T + bias1 -> P (f16) -----
__global__ __launch_bounds__(256) void s1_score(const f16* __restrict__ k16,
                                                const f16* __restrict__ agent16,
                                                const float* __restrict__ bias1,
                                                f16* __restrict__ P) {
    int bh = blockIdx.x;
    int h = bh % NHEAD;
    int wid = threadIdx.x >> 6;
    int lane = threadIdx.x & 63;
    int quad = lane >> 4, col = lane & 15;
    const f16* ag = agent16 + (size_t)bh * 4096;
    f16x8 afr[4][2];
#pragma unroll
    for (int mt = 0; mt < 4; ++mt)
#pragma unroll
        for (int ks = 0; ks < 2; ++ks)
            afr[mt][ks] = *(const f16x8*)(ag + (mt * 16 + col) * 64 + ks * 32 + quad * 8);
    const f16* kb = k16 + (size_t)bh * (NTOK * HDIM);
    f16* Pb = P + (size_t)bh * (64 * 800);
    for (int nt = wid; nt < 50; nt += 4) {
        int nn = nt * 16 + col;
        f16x8 b0 = *(const f16x8*)(kb + (size_t)nn * 64 + quad * 8);
        f16x8 b1 = *(const f16x8*)(kb + (size_t)nn * 64 + 32 + quad * 8);
#pragma unroll
        for (int mt = 0; mt < 4; ++mt) {
            f32x4 c = {0.f, 0.f, 0.f, 0.f};
            c = __builtin_amdgcn_mfma_f32_16x16x32_f16(afr[mt][0], b0, c, 0, 0, 0);
            c = __builtin_amdgcn_mfma_f32_16x16x32_f16(afr[mt][1], b1, c, 0, 0, 0);
#pragma unroll
            for (int r = 0; r < 4; ++r) {
                int a = mt * 16 + quad * 4 + r;
                float v = c[r];
                if (a < ANUM && nn < NTOK) v += bias1[(h * ANUM + a) * NTOK + nn];
                Pb[(size_t)a * 800 + nn] = (f16)v;
            }
        }
    }
}

// ---------------- generic in-place row softmax over f16 buffer -------------
__global__ __launch_bounds__(256) void softmax16(f16* __restrict__ buf, int total_rows,
                                                 int rpb_valid, int rpb_alloc,
                                                 int valid, int stride) {
    int wid = threadIdx.x >> 6, lane = threadIdx.x & 63;
    int r = blockIdx.x * 4 + wid;
    if (r >= total_rows) return;
    int bh = r / rpb_valid, i0 = r % rpb_valid;
    f16* p = buf + ((size_t)bh * rpb_alloc + i0) * stride;
    float m = -1e30f;
    for (int i = lane; i < valid; i += 64) m = fmaxf(m, (float)p[i]);
#pragma unroll
    for (int off = 32; off > 0; off >>= 1) m = fmaxf(m, __shfl_xor(m, off));
    float s = 0.f;
    for (int i = lane; i < valid; i += 64) s += __expf((float)p[i] - m);
#pragma unroll
    for (int off = 32; off > 0; off >>= 1) s += __shfl_xor(s, off);
    float inv = 1.0f / s;
    for (int i = lane; i < stride; i += 64) {
        float v = (i < valid) ? __expf((float)p[i] - m) * inv : 0.f;
        p[i] = (f16)v;
    }
}

// ---------------- stage1 PV: agentv^T = (P1 . V)^T ------------------------
__global__ __launch_bounds__(256) void s1_pv(const f16* __restrict__ P,
                                             const f16* __restrict__ vT,
                                             f16* __restrict__ avT) {
    int bh = blockIdx.x;
    int wid = threadIdx.x >> 6;
    int lane = threadIdx.x & 63;
    int quad = lane >> 4, col = lane & 15;
    const f16* Pb = P + (size_t)bh * 51200;
    const f16* Vt = vT + (size_t)bh * 51200;
    int m0 = wid * 16;
    f32x4 acc0 = {0.f, 0.f, 0.f, 0.f}, acc1 = acc0, acc2 = acc0, acc3 = acc0;
    for (int ks = 0; ks < 25; ++ks) {
        int k0 = ks * 32 + quad * 8;
        f16x8 a  = *(const f16x8*)(Pb + (size_t)(m0 + col) * 800 + k0);
        f16x8 b0 = *(const f16x8*)(Vt + (size_t)(col) * 800 + k0);
        f16x8 b1 = *(const f16x8*)(Vt + (size_t)(16 + col) * 800 + k0);
        f16x8 b2 = *(const f16x8*)(Vt + (size_t)(32 + col) * 800 + k0);
        f16x8 b3 = *(const f16x8*)(Vt + (size_t)(48 + col) * 800 + k0);
        acc0 = __builtin_amdgcn_mfma_f32_16x16x32_f16(a, b0, acc0, 0, 0, 0);
        acc1 = __builtin_amdgcn_mfma_f32_16x16x32_f16(a, b1, acc1, 0, 0, 0);
        acc2 = __builtin_amdgcn_mfma_f32_16x16x32_f16(a, b2, acc2, 0, 0, 0);
        acc3 = __builtin_amdgcn_mfma_f32_16x16x32_f16(a, b3, acc3, 0, 0, 0);
    }
    f16* av = avT + (size_t)bh * 4096;
#pragma unroll
    for (int dt = 0; dt < 4; ++dt) {
        f32x4 acc = (dt == 0) ? acc0 : (dt == 1) ? acc1 : (dt == 2) ? acc2 : acc3;
        f16x4 o;
#pragma unroll
        for (int r = 0; r < 4; ++r) o[r] = (f16)acc[r];
        *(f16x4*)(av + (size_t)(dt * 16 + col) * 64 + m0 + quad * 4) = o;
    }
}

// ---------------- stage2 scores: S2 = q . agent16^T + bias2 -> P (f16) -----
__global__ __launch_bounds__(256) void s2_score(const f16* __restrict__ q16,
                                                const f16* __restrict__ agent16,
                                                const float* __restrict__ bias2,
                                                f16* __restrict__ P) {
    int bh = blockIdx.x;
    int h = bh % NHEAD;
    int wid = threadIdx.x >> 6, lane = threadIdx.x & 63;
    int quad = lane >> 4, col = lane & 15;
    int qt = blockIdx.y * 4 + wid;
    if (qt >= 50) return;
    int n0 = qt * 16;
    const f16* qb = q16 + (size_t)bh * (NTOK * HDIM);
    f16x8 a0 = *(const f16x8*)(qb + (size_t)(n0 + col) * 64 + quad * 8);
    f16x8 a1 = *(const f16x8*)(qb + (size_t)(n0 + col) * 64 + 32 + quad * 8);
    const f16* ag = agent16 + (size_t)bh * 4096;
    f16* Pb = P + (size_t)bh * 51200;
#pragma unroll
    for (int at = 0; at < 4; ++at) {
        f16x8 b0 = *(const f16x8*)(ag + (at * 16 + col) * 64 + quad * 8);
        f16x8 b1 = *(const f16x8*)(ag + (at * 16 + col) * 64 + 32 + quad * 8);
        f32x4 c = {0.f, 0.f, 0.f, 0.f};
        c = __builtin_amdgcn_mfma_f32_16x16x32_f16(a0, b0, c, 0, 0, 0);
        c = __builtin_amdgcn_mfma_f32_16x16x32_f16(a1, b1, c, 0, 0, 0);
#pragma unroll
        for (int r = 0; r < 4; ++r) {
            int n = n0 + quad * 4 + r;
            int aa = at * 16 + col;
            float v = c[r];
            if (n < NTOK && aa < ANUM) v += bias2[((size_t)h * NTOK + n) * ANUM + aa];
            Pb[(size_t)n * 64 + aa] = (f16)v;
        }
    }
}

// ---------------- stage2 out: y = P2 . agentv -----------------------------
__global__ __launch_bounds__(256) void s2_out(const f16* __restrict__ P,
                                              const f16* __restrict__ avT,
                                              f16* __restrict__ y16) {
    int bh = blockIdx.x;
    int b = bh / NHEAD, h = bh % NHEAD;
    int wid = threadIdx.x >> 6, lane = threadIdx.x & 63;
    int quad = lane >> 4, col = lane & 15;
    int qt = blockIdx.y * 4 + wid;
    if (qt >= 50) return;
    int n0 = qt * 16;
    const f16* Pb = P + (size_t)bh * 51200;
    f16x8 a0 = *(const f16x8*)(Pb + (size_t)(n0 + col) * 64 + quad * 8);
    f16x8 a1 = *(const f16x8*)(Pb + (size_t)(n0 + col) * 64 + 32 + quad * 8);
    const f16* av = avT + (size_t)bh * 4096;
#pragma unroll
    for (int dt = 0; dt < 4; ++dt) {
        f16x8 b0 = *(const f16x8*)(av + (dt * 16 + col) * 64 + quad * 8);
        f16x8 b1 = *(const f16x8*)(av + (dt * 16 + col) * 64 + 32 + quad * 8);
        f32x4 c = {0.f, 0.f, 0.f, 0.f};
        c = __builtin_amdgcn_mfma_f32_16x16x32_f16(a0, b0, c, 0, 0, 0);
        c = __builtin_amdgcn_mfma_f32_16x16x32_f16(a1, b1, c, 0, 0, 0);
#pragma unroll
        for (int r = 0; r < 4; ++r) {
            int n = n0 + quad * 4 + r;
            if (n < NTOK)
                y16[((size_t)b * NTOK + n) * CDIM + h * HDIM + dt * 16 + col] = (f16)c[r];
        }
    }
}

// ---------------- depthwise 3x3 conv on V image tokens, add into y ---------
__global__ void dwc_kernel(const f16* __restrict__ v16, const float* __restrict__ w,
                           const float* __restrict__ bias, f16* __restrict__ y16) {
    int c = blockIdx.x * 256 + threadIdx.x;  // 0..767
    int p = blockIdx.y;                      // 0..783
    int b = blockIdx.z;                      // 0..63
    int h = c >> 6, d = c & 63;
    int y = p / WIN, x = p % WIN;
    const f16* vb = v16 + ((size_t)(b * NHEAD + h) * NTOK) * HDIM + d;
    float acc = bias[c];
#pragma unroll
    for (int ky = 0; ky < 3; ++ky) {
        int yy = y + ky - 1;
        if (yy < 0 || yy >= WIN) continue;
#pragma unroll
        for (int kx = 0; kx < 3; ++kx) {
            int xx = x + kx - 1;
            if (xx < 0 || xx >= WIN) continue;
            int nn = 1 + yy * WIN + xx;
            acc += (float)vb[(size_t)nn * HDIM] * w[(ky * 3 + kx) * CDIM + c];
        }
    }
    size_t yi = ((size_t)b * NTOK + 1 + p) * CDIM + c;
    y16[yi] = (f16)((float)y16[yi] + acc);
}

// ---------------- launch ---------------------------------------------------
extern "C" void kernel_launch(void* const* d_in, const int* in_sizes, int n_in,
                              void* d_out, int out_size, void* d_ws, size_t ws_size,
                              hipStream_t stream) {
    const float* x      = (const float*)d_in[0];
    const float* w_qkv  = (const float*)d_in[1];
    const float* w_proj = (const float*)d_in[2];
    const float* b_proj = (const float*)d_in[3];
    const float* dwc_w  = (const float*)d_in[4];
    const float* dwc_b  = (const float*)d_in[5];
    const float* an     = (const float*)d_in[6];
    const float* ah     = (const float*)d_in[7];
    const float* aw     = (const float*)d_in[8];
    const float* na     = (const float*)d_in[9];
    const float* ha     = (const float*)d_in[10];
    const float* wa     = (const float*)d_in[11];
    const float* ac     = (const float*)d_in[12];
    const float* ca     = (const float*)d_in[13];
    float* out = (float*)d_out;

    char* ws = (char*)d_ws;
    f16* q16   = (f16*)(ws + OFF_Q);
    f16* k16   = (f16*)(ws + OFF_K);
    f16* v16   = (f16*)(ws + OFF_V);
    f16* y16   = (f16*)(ws + OFF_Y);
    f16* vT    = (f16*)(ws + OFF_VT);
    f16* Pbuf  = (f16*)(ws + OFF_P);
    f16* agent16 = (f16*)(ws + OFF_AG);
    f16* avT   = (f16*)(ws + OFF_AVT);
    float* bias1 = (float*)(ws + OFF_B1);
    float* bias2 = (float*)(ws + OFF_B2);
    // overlays (lifetime-disjoint)
    f16* X16  = (f16*)(ws + OFF_P);    // x in fp16, consumed by mfma_qkv before P is written
    f16* W16  = (f16*)(ws + OFF_AVT);  // w_qkv fp16, consumed before avT is written
    f16* WP16 = (f16*)(ws + OFF_P);    // w_proj fp16, written after P fully consumed

    bias_kernel<<<(NHEAD * ANUM * NTOK + 255) / 256, 256, 0, stream>>>(
        an, ah, aw, ac, na, ha, wa, ca, bias1, bias2);

    // fp32 -> fp16 conversions
    cvt_kernel<<<(MROWS * CDIM / 4 + 255) / 256, 256, 0, stream>>>(x, X16, MROWS * CDIM / 4);
    cvt_kernel<<<(3 * CDIM * CDIM / 4 + 255) / 256, 256, 0, stream>>>(w_qkv, W16, 3 * CDIM * CDIM / 4);

    // qkv GEMM (MFMA) -> q16/k16/v16 (head-major) + vT
    mfma_qkv<<<dim3((MROWS + 127) / 128, (3 * CDIM) / 128), 256, 0, stream>>>(
        X16, W16, q16, k16, v16, vT);

    pool_kernel<<<BATCH * NHEAD * ANUM, 64, 0, stream>>>(q16, agent16);

    // stage 1: scores -> softmax (in place) -> PV
    s1_score<<<BATCH * NHEAD, 256, 0, stream>>>(k16, agent16, bias1, Pbuf);
    softmax16<<<(BATCH * NHEAD * ANUM + 3) / 4, 256, 0, stream>>>(
        Pbuf, BATCH * NHEAD * ANUM, ANUM, 64, NTOK, 800);
    s1_pv<<<BATCH * NHEAD, 256, 0, stream>>>(Pbuf, vT, avT);

    // stage 2: scores -> softmax (in place) -> out (reuses Pbuf)
    s2_score<<<dim3(BATCH * NHEAD, 13), 256, 0, stream>>>(q16, agent16, bias2, Pbuf);
    softmax16<<<(BATCH * NHEAD * NTOK + 3) / 4, 256, 0, stream>>>(
        Pbuf, BATCH * NHEAD * NTOK, NTOK, 800, ANUM, 64);
    s2_out<<<dim3(BATCH * NHEAD, 13), 256, 0, stream>>>(Pbuf, avT, y16);

    dwc_kernel<<<dim3(CDIM / 256, WIN * WIN, BATCH), 256, 0, stream>>>(v16, dwc_w, dwc_b, y16);

    // output projection (MFMA)
    cvt_kernel<<<(CDIM * CDIM / 4 + 255) / 256, 256, 0, stream>>>(w_proj, WP16, CDIM * CDIM / 4);
    mfma_proj<<<dim3((MROWS + 127) / 128, CDIM / 128), 256, 0, stream>>>(y16, WP16, b_proj, out);
}